// Round 12
// baseline (262.231 us; speedup 1.0000x reference)
//
#include <hip/hip_runtime.h>

// Causal self-attention fwd: B=2 S=4096 H=16 D=64, fp32 in/out, bf16 MFMA compute.
// R12: concurrency fix. Evidence R6/R9/R11: duration pinned at ~170-182us while occupancy
// hovered ~8 waves/CU (paired blocks: only 512x4 waves; remapped blocks: length-imbalanced,
// concurrency decays to the longest block -> time-avg 8.25 waves/CU = measured 24%).
// Change: QBLK=256, 8 waves/block (512 thr), pairing {qt,15-qt} -> 512 blocks ALL exactly
// 68 kv-steps; 2 blocks/CU x 8 waves = 16 waves/CU SUSTAINED, uniform finish.
// Staging split-role (R3-validated): thr 0-255 K (16-wide row chunks, 2-way write overlap
// = free), thr 256-511 V (4x4 transpose micro-tiles, R11-validated XOR swizzle).
// Per-wave compute identical to R11 (rt=2, swapped QK^T, in-reg P, v_max3, shfl rescale).

#define S_LEN 4096
#define NHEAD 16
#define HDIM 64
#define QBLK 256
#define KVBLK 64
#define NPAIR 16
#define LDK 72
#define ROWSTRIDE (3 * NHEAD * HDIM)  // 3072 floats between consecutive s

using bf16x8 = __attribute__((ext_vector_type(8))) short;
using bf16x4 = __attribute__((ext_vector_type(4))) short;
using f32x4  = __attribute__((ext_vector_type(4))) float;

#define MFMA32(A, B, C) __builtin_amdgcn_mfma_f32_16x16x32_bf16((A), (B), (C), 0, 0, 0)
#define MFMA16(A, B, C) __builtin_amdgcn_mfma_f32_16x16x16bf16_1k((A), (B), (C), 0, 0, 0)

#if __has_builtin(__builtin_amdgcn_exp2f)
#define EXP2F(x) __builtin_amdgcn_exp2f(x)
#else
#define EXP2F(x) exp2f(x)
#endif

__device__ __forceinline__ int f2bf2(float lo, float hi) {
  int r;
  asm("v_cvt_pk_bf16_f32 %0, %1, %2" : "=v"(r) : "v"(lo), "v"(hi));
  return r;  // low 16 = bf16(lo), high 16 = bf16(hi)
}

__device__ __forceinline__ float max3f(float a, float b, float c) {
  float d;
  asm("v_max3_f32 %0, %1, %2, %3" : "=v"(d) : "v"(a), "v"(b), "v"(c));
  return d;
}

__global__ __launch_bounds__(512, 2)
void attn_fwd(const float* __restrict__ qkv, float* __restrict__ out) {
  __shared__ short Ks[KVBLK][LDK] __attribute__((aligned(16)));   // K[kv][d] bf16
  __shared__ short VTs[HDIM][LDK] __attribute__((aligned(16)));   // V^T[d][kv] bf16, col-swizzled

  const int qp0  = blockIdx.x;   // pair index 0..15
  const int bh   = blockIdx.y;
  const int b    = bh >> 4;   // H=16
  const int h    = bh & 15;
  const int tid  = threadIdx.x;
  const int wid  = tid >> 6;   // 0..7
  const int lane = tid & 63;
  const int lq   = lane & 15;
  const int lg   = lane >> 4;

  const float* basep = qkv + (size_t)b * S_LEN * ROWSTRIDE + h * HDIM;
  const float* kbase = basep + NHEAD * HDIM;       // t=1
  const float* vbase = basep + 2 * NHEAD * HDIM;   // t=2

  // ---- split-role staging (R3-validated): thr 0-255 stage K, thr 256-511 stage V^T ----
  const bool isK = tid < 256;
  const int st   = tid & 255;
  const int krow = st >> 2;            // K: one row, 16 consecutive d
  const int kcol = (st & 3) * 16;
  const int vrb  = (st >> 4) * 4;      // V: 4 rows x 4 cols micro-tile
  const int vcb  = (st & 15) * 4;
  const int vcol = 4 * ((vrb >> 2) ^ (vcb >> 3));  // R11-validated XOR swizzle (write side)

  f32x4 sreg[4];
  auto load_tile = [&](int kvt) {
    if (isK) {
      const float* p = kbase + (size_t)(kvt * KVBLK + krow) * ROWSTRIDE + kcol;
      sreg[0] = *reinterpret_cast<const f32x4*>(p);
      sreg[1] = *reinterpret_cast<const f32x4*>(p + 4);
      sreg[2] = *reinterpret_cast<const f32x4*>(p + 8);
      sreg[3] = *reinterpret_cast<const f32x4*>(p + 12);
    } else {
      const float* p = vbase + (size_t)(kvt * KVBLK + vrb) * ROWSTRIDE + vcb;
#pragma unroll
      for (int i = 0; i < 4; ++i)
        sreg[i] = *reinterpret_cast<const f32x4*>(p + (size_t)i * ROWSTRIDE);
    }
  };
  auto store_tile = [&]() {
    if (isK) {
      union { bf16x8 v; int w[4]; } u0, u1;
      u0.w[0] = f2bf2(sreg[0][0], sreg[0][1]); u0.w[1] = f2bf2(sreg[0][2], sreg[0][3]);
      u0.w[2] = f2bf2(sreg[1][0], sreg[1][1]); u0.w[3] = f2bf2(sreg[1][2], sreg[1][3]);
      u1.w[0] = f2bf2(sreg[2][0], sreg[2][1]); u1.w[1] = f2bf2(sreg[2][2], sreg[2][3]);
      u1.w[2] = f2bf2(sreg[3][0], sreg[3][1]); u1.w[3] = f2bf2(sreg[3][2], sreg[3][3]);
      *reinterpret_cast<bf16x8*>(&Ks[krow][kcol])     = u0.v;
      *reinterpret_cast<bf16x8*>(&Ks[krow][kcol + 8]) = u1.v;
    } else {
#pragma unroll
      for (int e = 0; e < 4; ++e) {
        union { bf16x4 v; int w[2]; } vv;
        vv.w[0] = f2bf2(sreg[0][e], sreg[1][e]);
        vv.w[1] = f2bf2(sreg[2][e], sreg[3][e]);
        *reinterpret_cast<bf16x4*>(&VTs[vcb + e][vcol]) = vv.v;
      }
    }
  };

  const float SC = 0.18033688011112042f;  // (1/8) * log2(e)

#pragma unroll 1
  for (int pi = 0; pi < 2; ++pi) {
    const int qt = (pi == 0) ? qp0 : (NPAIR - 1 - qp0);
    const int wq = qt * QBLK + wid * 32;  // this wave's first q row (32 rows)

    // ---- Q fragments (B-operand: col=q=lq, k=d=8*lg+jj+32*t) for rt=0,1 ----
    bf16x8 qf[2][2];
#pragma unroll
    for (int rt = 0; rt < 2; ++rt) {
      const float* qp = basep + (size_t)(wq + rt * 16 + lq) * ROWSTRIDE + 8 * lg;
#pragma unroll
      for (int t = 0; t < 2; ++t) {
        f32x4 x0 = *reinterpret_cast<const f32x4*>(qp + 32 * t);
        f32x4 x1 = *reinterpret_cast<const f32x4*>(qp + 32 * t + 4);
        union { bf16x8 v; int w[4]; } uq;
        uq.w[0] = f2bf2(x0[0] * SC, x0[1] * SC);
        uq.w[1] = f2bf2(x0[2] * SC, x0[3] * SC);
        uq.w[2] = f2bf2(x1[0] * SC, x1[1] * SC);
        uq.w[3] = f2bf2(x1[2] * SC, x1[3] * SC);
        qf[rt][t] = uq.v;
      }
    }

    f32x4 acc[2][4];
#pragma unroll
    for (int rt = 0; rt < 2; ++rt)
#pragma unroll
      for (int dt = 0; dt < 4; ++dt)
        acc[rt][dt] = (f32x4){0.f, 0.f, 0.f, 0.f};

    float mrun[2] = {-1e30f, -1e30f};
    float lrun[2] = {0.f, 0.f};

    const int nkv = 4 * qt + 4;  // causal: kv tiles 0 .. 4*qt+3
    load_tile(0);

    for (int kvt = 0; kvt < nkv; ++kvt) {
      __syncthreads();  // previous tile's LDS reads complete (also guards pass boundary)
      store_tile();
      __syncthreads();  // tile visible to all waves
      if (kvt + 1 < nkv) load_tile(kvt + 1);  // prefetch overlaps compute

      const int kvb = kvt * KVBLK;
      if (kvb > wq + 31) continue;  // tile fully masked for this wave's rows

      // ---- QK^T (swapped: A=K, B=Q -> C[kv=c*16+4*lg+r][q=lq]) ----
      f32x4 sc[2][4];
#pragma unroll
      for (int rt = 0; rt < 2; ++rt)
#pragma unroll
        for (int c = 0; c < 4; ++c)
          sc[rt][c] = (f32x4){0.f, 0.f, 0.f, 0.f};

#pragma unroll
      for (int c = 0; c < 4; ++c) {
        bf16x8 k0 = *reinterpret_cast<const bf16x8*>(&Ks[c * 16 + lq][8 * lg]);
        bf16x8 k1 = *reinterpret_cast<const bf16x8*>(&Ks[c * 16 + lq][8 * lg + 32]);
#pragma unroll
        for (int rt = 0; rt < 2; ++rt) {
          sc[rt][c] = MFMA32(k0, qf[rt][0], sc[rt][c]);
          sc[rt][c] = MFMA32(k1, qf[rt][1], sc[rt][c]);
        }
      }

      // causal mask (diagonal-region tiles only)
      if (kvb + KVBLK - 1 > wq) {
#pragma unroll
        for (int rt = 0; rt < 2; ++rt) {
          const int q0 = wq + rt * 16 + lq;
#pragma unroll
          for (int c = 0; c < 4; ++c)
#pragma unroll
            for (int r = 0; r < 4; ++r)
              if (kvb + c * 16 + 4 * lg + r > q0) sc[rt][c][r] = -1e30f;
        }
      }

      // ---- online softmax (per q-row = lane lq), P stays in registers ----
      bf16x4 pf[2][4];
      float alpha[2];
#pragma unroll
      for (int rt = 0; rt < 2; ++rt) {
        float v0 = max3f(sc[rt][0][0], sc[rt][0][1], sc[rt][0][2]);
        float v1 = max3f(sc[rt][0][3], sc[rt][1][0], sc[rt][1][1]);
        float v2 = max3f(sc[rt][1][2], sc[rt][1][3], sc[rt][2][0]);
        float v3 = max3f(sc[rt][2][1], sc[rt][2][2], sc[rt][2][3]);
        float v4 = max3f(sc[rt][3][0], sc[rt][3][1], sc[rt][3][2]);
        float tm = fmaxf(max3f(v0, v1, v2), max3f(v3, v4, sc[rt][3][3]));
        tm = fmaxf(tm, __shfl_xor(tm, 16));
        tm = fmaxf(tm, __shfl_xor(tm, 32));
        const float newm = fmaxf(mrun[rt], tm);
        alpha[rt] = EXP2F(mrun[rt] - newm);
        mrun[rt] = newm;

        float ts = 0.f;
#pragma unroll
        for (int c = 0; c < 4; ++c) {
          float p0 = EXP2F(sc[rt][c][0] - newm);
          float p1 = EXP2F(sc[rt][c][1] - newm);
          float p2 = EXP2F(sc[rt][c][2] - newm);
          float p3 = EXP2F(sc[rt][c][3] - newm);
          ts += (p0 + p1) + (p2 + p3);
          union { bf16x4 v; int w[2]; } pp;
          pp.w[0] = f2bf2(p0, p1);
          pp.w[1] = f2bf2(p2, p3);
          pf[rt][c] = pp.v;
        }
        ts += __shfl_xor(ts, 16);
        ts += __shfl_xor(ts, 32);
        lrun[rt] = lrun[rt] * alpha[rt] + ts;
      }

      // ---- rescale acc: alpha lives per q=lq, acc rows are q=4*lg+r -> fetch via shfl ----
#pragma unroll
      for (int rt = 0; rt < 2; ++rt) {
        const float a0 = __shfl(alpha[rt], 4 * lg + 0);
        const float a1 = __shfl(alpha[rt], 4 * lg + 1);
        const float a2 = __shfl(alpha[rt], 4 * lg + 2);
        const float a3 = __shfl(alpha[rt], 4 * lg + 3);
#pragma unroll
        for (int dt = 0; dt < 4; ++dt) {
          acc[rt][dt][0] *= a0;
          acc[rt][dt][1] *= a1;
          acc[rt][dt][2] *= a2;
          acc[rt][dt][3] *= a3;
        }
      }

      // ---- PV: A=P from regs, B=V^T from LDS (swizzled read), C[q=4*lg+r][d=dt*16+lq] ----
#pragma unroll
      for (int dt = 0; dt < 4; ++dt) {
        const int f = (2 * dt + (lq >> 3)) & 7;  // (row>>3) for row = dt*16+lq
#pragma unroll
        for (int c = 0; c < 4; ++c) {
          bf16x4 vf = *reinterpret_cast<const bf16x4*>(&VTs[dt * 16 + lq][4 * ((4 * c + lg) ^ f)]);
          acc[0][dt] = MFMA16(pf[0][c], vf, acc[0][dt]);
          acc[1][dt] = MFMA16(pf[1][c], vf, acc[1][dt]);
        }
      }
    }

    // ---- epilogue: normalize and store (fp32 out) ----
#pragma unroll
    for (int rt = 0; rt < 2; ++rt) {
      const float l0 = __shfl(lrun[rt], 4 * lg + 0);
      const float l1 = __shfl(lrun[rt], 4 * lg + 1);
      const float l2 = __shfl(lrun[rt], 4 * lg + 2);
      const float l3 = __shfl(lrun[rt], 4 * lg + 3);
      const f32x4 linv = {1.f / l0, 1.f / l1, 1.f / l2, 1.f / l3};
#pragma unroll
      for (int dt = 0; dt < 4; ++dt) {
#pragma unroll
        for (int r = 0; r < 4; ++r) {
          out[(size_t)(b * S_LEN + wq + rt * 16 + 4 * lg + r) * (NHEAD * HDIM) + h * HDIM + dt * 16 + lq] =
              acc[rt][dt][r] * linv[r];
        }
      }
    }
  }
}

extern "C" void kernel_launch(void* const* d_in, const int* in_sizes, int n_in,
                              void* d_out, int out_size, void* d_ws, size_t ws_size,
                              hipStream_t stream) {
  const float* qkv = (const float*)d_in[0];
  float* o = (float*)d_out;
  dim3 grid(NPAIR, 2 * NHEAD);  // (q-supertile pairs, B*H)
  attn_fwd<<<grid, 512, 0, stream>>>(qkv, o);
}